// Round 2
// baseline (12068.000 us; speedup 1.0000x reference)
//
#include <hip/hip_runtime.h>
#include <hip/hip_bf16.h>
#include <math.h>

typedef __hip_bfloat16 bf16;

// ---------------------------------------------------------------- dtype detect
// Reads first nwords dwords of xyzs. If data is f32, the LOW halfword of each
// dword is float mantissa bits -> as bf16 has ~uniform exponent -> ~25% have
// exp>=0xC0 (|v|>=2^65) or 0xFF. True bf16 N(0,1) data: ~0 such. flag=1 -> f32.
__global__ void k_detect(const unsigned int* __restrict__ w, int nwords, int* __restrict__ flag){
  __shared__ int cnt;
  if(threadIdx.x==0) cnt=0;
  __syncthreads();
  int local=0;
  for(int i=threadIdx.x;i<nwords;i+=256){
    unsigned int v=w[i];
    int e=(v>>7)&0xFF;           // exponent field of low-halfword bf16
    if(e>=0xC0) local++;
  }
  atomicAdd(&cnt, local);
  __syncthreads();
  if(threadIdx.x==0) flag[0] = (cnt > (nwords>>3)) ? 1 : 0;
}

// ---------------------------------------------------------------- utilities
__global__ void k_cvt(const void* __restrict__ s, float* __restrict__ d, int n,
                      const int* __restrict__ flag){
  int i = blockIdx.x*256 + threadIdx.x;
  if(i>=n) return;
  if(*flag) d[i] = ((const float*)s)[i];
  else      d[i] = __bfloat162float(((const bf16*)s)[i]);
}

__global__ void k_zero(float* __restrict__ p, int n){
  int i = blockIdx.x*256 + threadIdx.x;
  if(i<n) p[i]=0.f;
}

// ---------------------------------------------------------------- FPS
template<int P>
__global__ __launch_bounds__(256) void k_fps(
    const float* __restrict__ xyz, int L, int N, int m,
    int c0,int c1,int c2,int c3, int T, float* __restrict__ anchors)
{
  int prob = blockIdx.x;
  int b = prob / T, tt = prob % T;
  int f = (tt==0)?c0:(tt==1)?c1:(tt==2)?c2:c3;
  const float* src = xyz + ((size_t)(b*L + f))*N*3;
  float* anc = anchors + ((size_t)(b*T + tt))*m*3;
  int tid = threadIdx.x;
  float px[P],py[P],pz[P],mind[P];
#pragma unroll
  for(int j=0;j<P;j++){
    int p = tid + j*256;
    px[j]=src[3*p]; py[j]=src[3*p+1]; pz[j]=src[3*p+2];
    mind[j]=1e10f;
  }
  __shared__ float sv[4]; __shared__ int si[4]; __shared__ float sl[3];
  if(tid==0){ anc[0]=px[0]; anc[1]=py[0]; anc[2]=pz[0]; sl[0]=px[0]; sl[1]=py[0]; sl[2]=pz[0]; }
  __syncthreads();
  float lx=sl[0], ly=sl[1], lz=sl[2];
  for(int it=1; it<m; ++it){
    float bv=-1.f, bx=0.f,by=0.f,bz=0.f; int bi=0;
#pragma unroll
    for(int j=0;j<P;j++){
#pragma clang fp contract(off)
      float dx=px[j]-lx, dy=py[j]-ly, dz=pz[j]-lz;
      float d2=dx*dx+dy*dy+dz*dz;
      float mv=mind[j]; if(d2<mv) mv=d2; mind[j]=mv;
      if(mv>bv){ bv=mv; bi=tid+j*256; bx=px[j]; by=py[j]; bz=pz[j]; }
    }
    float rv=bv; int ri=bi;
#pragma unroll
    for(int o=32;o>0;o>>=1){
      float ov=__shfl_down(rv,o); int oi=__shfl_down(ri,o);
      if(ov>rv || (ov==rv && oi<ri)){ rv=ov; ri=oi; }
    }
    if((tid&63)==0){ sv[tid>>6]=rv; si[tid>>6]=ri; }
    __syncthreads();
    float wv=sv[0]; int wi=si[0];
#pragma unroll
    for(int q=1;q<4;q++){
      if(sv[q]>wv || (sv[q]==wv && si[q]<wi)){ wv=sv[q]; wi=si[q]; }
    }
    if(tid==(wi&255)){
      sl[0]=bx; sl[1]=by; sl[2]=bz;
      anc[3*it]=bx; anc[3*it+1]=by; anc[3*it+2]=bz;
    }
    __syncthreads();
    lx=sl[0]; ly=sl[1]; lz=sl[2];
  }
}

// ---------------------------------------------------------------- ball query
__global__ __launch_bounds__(256) void k_bq(
    const float* __restrict__ pts, const float* __restrict__ anc,
    int* __restrict__ out, int N, int m, float r2,
    size_t pBS, size_t aBS)
{
  int chunks = (m+255)>>8;
  int b = blockIdx.x / chunks;
  int a = (blockIdx.x % chunks)*256 + threadIdx.x;
  const float* Pb = pts + (size_t)b*pBS;
  bool act = a < m;
  float ax=0,ay=0,az=0;
  int* o = out + ((size_t)b*m + (size_t)(act?a:0))*9;
  if(act){ const float* A = anc + (size_t)b*aBS + (size_t)a*3; ax=A[0]; ay=A[1]; az=A[2]; }
  int cnt = act?0:9, first=0;
  __shared__ float sp[768];
  for(int base=0; base<N; base+=256){
    for(int t=threadIdx.x; t<768; t+=256) sp[t]=Pb[(size_t)base*3+t];
    __syncthreads();
    for(int q=0;q<256;q++){
#pragma clang fp contract(off)
      float dx=sp[3*q]-ax, dy=sp[3*q+1]-ay, dz=sp[3*q+2]-az;
      float d2=dx*dx+dy*dy+dz*dz;
      if(d2<r2 && cnt<9){
        int p=base+q;
        if(cnt==0) first=p;
        o[cnt]=p; cnt++;
      }
    }
    if(__syncthreads_and(cnt>=9)) break;
  }
  if(act){ for(int k=cnt;k<9;k++) o[k]=first; }
}

// ---------------------------------------------------------------- layer 0 part
__global__ void k_part0(
    const float* __restrict__ pts, const float* __restrict__ anc,
    const int* __restrict__ idx, const float* __restrict__ Wd,
    float* __restrict__ nf, int m, int mid, int ld, int nmask,
    size_t pBS, size_t aBS)
{
  int row = blockIdx.x;
  int b = row/m, mm = row - b*m;
  int o = threadIdx.x;
  const float* A = anc + (size_t)b*aBS + (size_t)mm*3;
  float ax=A[0], ay=A[1], az=A[2];
  float w0=0,w1=0,w2=0;
  if(o<mid){ w0=Wd[3*o]; w1=Wd[3*o+1]; w2=Wd[3*o+2]; }
  const int* id = idx + (size_t)row*9;
  const float* Pb = pts + (size_t)b*pBS;
  float acc=0.f;
  for(int k=0;k<9;k++){
    int p=id[k] & nmask;
    const float* q = Pb + (size_t)p*3;
    float dx=q[0]-ax, dy=q[1]-ay, dz=q[2]-az;
    acc += dx*w0+dy*w1+dz*w2;
  }
  if(o<mid) nf[(size_t)row*ld + o] = acc;
}

// ---------------------------------------------------------------- fused pair kernel
__global__ __launch_bounds__(256) void k_pair(
    const float* __restrict__ feats, const float* __restrict__ pts,
    const float* __restrict__ anc, const int* __restrict__ idx,
    const float* __restrict__ Wf, const float* __restrict__ Wd,
    float* __restrict__ nf, int m, int cin, int mid, int ld, int jofs, int nmask,
    size_t fBS, size_t pBS, size_t aBS)
{
  __shared__ alignas(16) float As[16][64];
  __shared__ alignas(16) float Bs[16][128];
  __shared__ float dispS[64][3];
  __shared__ float WdS[128][3];
  __shared__ float ancS[64][3];
  int tid=threadIdx.x;
  int tx=tid&15, ty=tid>>4;
  int rowBase=blockIdx.x*64, colBase=blockIdx.y*128;
  int b=rowBase/m;
  if(tid<64){
    int mm=(rowBase+tid)%m;
    const float* A0=anc+(size_t)b*aBS+(size_t)mm*3;
    ancS[tid][0]=A0[0]; ancS[tid][1]=A0[1]; ancS[tid][2]=A0[2];
  }
  if(tid<128){
    int o=colBase+tid;
    if(o<mid){ WdS[tid][0]=Wd[3*o]; WdS[tid][1]=Wd[3*o+1]; WdS[tid][2]=Wd[3*o+2]; }
    else { WdS[tid][0]=0; WdS[tid][1]=0; WdS[tid][2]=0; }
  }
  float acc[4][8];
#pragma unroll
  for(int i=0;i<4;i++)
#pragma unroll
    for(int j=0;j<8;j++) acc[i][j]=0.f;
  const float* fB=feats+(size_t)b*fBS;
  const float* pB=pts+(size_t)b*pBS;
  int lrow=tid&63, lcq=tid>>6;
  int orow=tid&127, ohalf=tid>>7;
  int nct=cin>>4;
  const int* idxB = idx + (size_t)rowBase*9;
  for(int k=0;k<9;k++){
    __syncthreads();
    if(tid<64){
      int p = idxB[tid*9 + k] & nmask;
      const float* q = pB + (size_t)p*3;
      dispS[tid][0]=q[0]-ancS[tid][0];
      dispS[tid][1]=q[1]-ancS[tid][1];
      dispS[tid][2]=q[2]-ancS[tid][2];
    }
    float acc2[4][8];
#pragma unroll
    for(int i=0;i<4;i++)
#pragma unroll
      for(int j=0;j<8;j++) acc2[i][j]=0.f;
    for(int ct=0;ct<nct;ct++){
      __syncthreads();
      {
        int p = idxB[lrow*9 + k] & nmask;
        const float4 v = *(const float4*)(fB + (size_t)p*cin + (ct<<4) + (lcq<<2));
        As[(lcq<<2)+0][lrow]=v.x; As[(lcq<<2)+1][lrow]=v.y;
        As[(lcq<<2)+2][lrow]=v.z; As[(lcq<<2)+3][lrow]=v.w;
      }
#pragma unroll
      for(int h=0;h<2;h++){
        int c0=(ohalf<<3)+(h<<2);
        int og=colBase+orow;
        float4 v=make_float4(0.f,0.f,0.f,0.f);
        if(og<mid) v=*(const float4*)(Wf + (size_t)og*cin + (ct<<4) + c0);
        Bs[c0+0][orow]=v.x; Bs[c0+1][orow]=v.y; Bs[c0+2][orow]=v.z; Bs[c0+3][orow]=v.w;
      }
      __syncthreads();
#pragma unroll
      for(int c=0;c<16;c++){
        float4 a4=*(const float4*)&As[c][ty<<2];
        float4 b0=*(const float4*)&Bs[c][tx<<3];
        float4 b1=*(const float4*)&Bs[c][(tx<<3)+4];
        float av[4]={a4.x,a4.y,a4.z,a4.w};
        float bw[8]={b0.x,b0.y,b0.z,b0.w,b1.x,b1.y,b1.z,b1.w};
#pragma unroll
        for(int i=0;i<4;i++)
#pragma unroll
          for(int j=0;j<8;j++) acc2[i][j]+=av[i]*bw[j];
      }
    }
#pragma unroll
    for(int i=0;i<4;i++){
      float dx=dispS[(ty<<2)+i][0], dy=dispS[(ty<<2)+i][1], dz=dispS[(ty<<2)+i][2];
#pragma unroll
      for(int j=0;j<8;j++){
        int oc=(tx<<3)+j;
        float d=dx*WdS[oc][0]+dy*WdS[oc][1]+dz*WdS[oc][2];
        acc[i][j]+=acc2[i][j]*d;
      }
    }
  }
#pragma unroll
  for(int i=0;i<4;i++){
    int r=rowBase+(ty<<2)+i;
#pragma unroll
    for(int j=0;j<8;j++){
      int o=colBase+(tx<<3)+j;
      if(o<mid) nf[(size_t)r*ld + jofs + o]=acc[i][j];
    }
  }
}

// ---------------------------------------------------------------- BatchNorm
__global__ void k_bnstat(const float* __restrict__ nf, int M, int C, float* __restrict__ sums){
  int c = blockIdx.x*256 + threadIdx.x;
  if(c>=C) return;
  int rows = M>>5;
  int r0 = blockIdx.y*rows, r1 = r0+rows;
  float s=0.f, s2=0.f;
  for(int r=r0;r<r1;r++){
    float v=nf[(size_t)r*C+c];
    s+=v; s2+=v*v;
  }
  atomicAdd(&sums[c], s);
  atomicAdd(&sums[C+c], s2);
}

__global__ void k_bnapply(float* __restrict__ nf, const float* __restrict__ sums, int M, int C){
  long long i = (long long)blockIdx.x*256 + threadIdx.x;
  long long tot = (long long)M*C;
  if(i>=tot) return;
  int c = (int)(i % (long long)C);
  float mean = sums[c]/(float)M;
  float var = sums[C+c]/(float)M - mean*mean;
  if(var<0.f) var=0.f;
  float v = (nf[i]-mean)/sqrtf(var+1e-5f);
  nf[i] = v>0.f? v:0.f;
}

// ---------------------------------------------------------------- generic GEMM
template<int TN, bool ALIGNED, bool RELU, bool DYN>
__global__ __launch_bounds__(256) void k_gemm(
    const float* __restrict__ Ag, const float* __restrict__ Wg,
    const float* __restrict__ bias, void* __restrict__ out,
    int M, int K, int N, int mloc, size_t oBS, const int* __restrict__ oflag)
{
  constexpr int CW = TN/16;
  __shared__ alignas(16) float As[16][64];
  __shared__ alignas(16) float Bs[16][TN];
  int tid=threadIdx.x, tx=tid&15, ty=tid>>4;
  int rowBase=blockIdx.x*64, colBase=blockIdx.y*TN;
  bool f32m = DYN ? (*oflag!=0) : true;
  float acc[4][CW];
#pragma unroll
  for(int i=0;i<4;i++)
#pragma unroll
    for(int j=0;j<CW;j++) acc[i][j]=0.f;
  int lrow=tid&63, lcq=tid>>6;
  int nct=(K+15)>>4;
  for(int ct=0;ct<nct;ct++){
    __syncthreads();
    {
      int r=rowBase+lrow, c0=(ct<<4)+(lcq<<2);
      if(ALIGNED){
        float4 v=*(const float4*)(Ag+(size_t)r*K+c0);
        As[(lcq<<2)+0][lrow]=v.x; As[(lcq<<2)+1][lrow]=v.y;
        As[(lcq<<2)+2][lrow]=v.z; As[(lcq<<2)+3][lrow]=v.w;
      } else {
#pragma unroll
        for(int q=0;q<4;q++){
          int c=c0+q;
          As[(lcq<<2)+q][lrow] = (c<K)? Ag[(size_t)r*K+c] : 0.f;
        }
      }
    }
    if(TN==64){
      int og=colBase+lrow, c0=(ct<<4)+(lcq<<2);
      if(ALIGNED){
        float4 v=*(const float4*)(Wg+(size_t)og*K+c0);
        Bs[(lcq<<2)+0][lrow]=v.x; Bs[(lcq<<2)+1][lrow]=v.y;
        Bs[(lcq<<2)+2][lrow]=v.z; Bs[(lcq<<2)+3][lrow]=v.w;
      } else {
#pragma unroll
        for(int q=0;q<4;q++){
          int c=c0+q;
          Bs[(lcq<<2)+q][lrow] = (c<K)? Wg[(size_t)og*K+c] : 0.f;
        }
      }
    } else {
      int orow=tid&127, ohalf=tid>>7;
      int og=colBase+orow;
#pragma unroll
      for(int h=0;h<2;h++){
        int c0=(ohalf<<3)+(h<<2);
        int cg=(ct<<4)+c0;
        if(ALIGNED){
          float4 v=*(const float4*)(Wg+(size_t)og*K+cg);
          Bs[c0+0][orow]=v.x; Bs[c0+1][orow]=v.y; Bs[c0+2][orow]=v.z; Bs[c0+3][orow]=v.w;
        } else {
#pragma unroll
          for(int q=0;q<4;q++){
            int c=cg+q;
            Bs[c0+q][orow]=(c<K)? Wg[(size_t)og*K+c]:0.f;
          }
        }
      }
    }
    __syncthreads();
#pragma unroll
    for(int c=0;c<16;c++){
      float4 a4=*(const float4*)&As[c][ty<<2];
      float av[4]={a4.x,a4.y,a4.z,a4.w};
      float bw[CW];
#pragma unroll
      for(int j0=0;j0<CW;j0+=4){
        float4 b4=*(const float4*)&Bs[c][tx*CW+j0];
        bw[j0]=b4.x; bw[j0+1]=b4.y; bw[j0+2]=b4.z; bw[j0+3]=b4.w;
      }
#pragma unroll
      for(int i=0;i<4;i++)
#pragma unroll
        for(int j=0;j<CW;j++) acc[i][j]+=av[i]*bw[j];
    }
  }
#pragma unroll
  for(int i=0;i<4;i++){
    int r=rowBase+(ty<<2)+i;
    int rb=r/mloc, rm=r-rb*mloc;
    size_t obase=(size_t)rb*oBS + (size_t)rm*N;
#pragma unroll
    for(int j=0;j<CW;j++){
      int o=colBase+tx*CW+j;
      float v=acc[i][j];
      if(bias) v+=bias[o];
      if(RELU) v=fmaxf(v,0.f);
      if(DYN && !f32m) ((bf16*)out)[obase+o]=__float2bfloat16(v);
      else             ((float*)out)[obase+o]=v;
    }
  }
}

// ---------------------------------------------------------------- host
extern "C" void kernel_launch(void* const* d_in, const int* in_sizes, int n_in,
                              void* d_out, int out_size, void* d_ws, size_t ws_size,
                              hipStream_t stream) {
  (void)in_sizes; (void)n_in; (void)out_size; (void)ws_size;

  const int di[6] = {2,4,7,10,13,16};
  const int fi[6] = {-1,5,8,11,14,17};
  const int ti[6] = {3,6,9,12,15,18};

  const int midv[6]={45,96,192,384,768,1536};
  const int cinv[6]={0,64,128,256,512,1024};
  const int coutv[6]={64,128,256,512,1024,2048};
  const int tkv[6]={1,3,3,3,3,1};
  const int Nv[6]={2048,1024,512,512,256,256};
  const int mv[6]={1024,512,512,256,256,128};
  const int Lv[6]={4,4,2,2,1,1};
  const int Tv[6]={4,2,2,1,1,1};
  const float rrv[6]={1.5f,3.f,3.f,6.f,6.f,6.f};

  float* ws=(float*)d_ws;
  size_t off=0;
  auto A=[&](size_t n)->float*{ float* p=ws+off; off+=(n+63)&~(size_t)63; return p; };

  int* flag=(int*)A(64);

  float *Wd[6], *Wf[6], *Wt[6];
  for(int l=0;l<6;l++){
    Wd[l]=A((size_t)midv[l]*3);
    Wf[l]= cinv[l]? A((size_t)midv[l]*cinv[l]) : nullptr;
    Wt[l]=A((size_t)coutv[l]*tkv[l]*midv[l]);
  }
  float* fcw=A(1024ull*2048);
  float* fcb=A(1024);

  float* X[7];
  X[0]=A(32ull*4*2048*3);
  for(int l=0;l<6;l++) X[l+1]=A((size_t)32*Tv[l]*mv[l]*3);

  float* FA=A(8388608);
  float* FB=A(8388608);
  float* F[7]; F[0]=nullptr;
  for(int l=0;l<6;l++) F[l+1]=(l%2==0)?FA:FB;

  float* nf=A(18874368);
  float* sums=A(4608);
  int* bq=(int*)A(32ull*1024*9);

  // ---- detect input dtype (f32 vs bf16), then convert
  k_detect<<<dim3(1),dim3(256),0,stream>>>((const unsigned int*)d_in[0], 4096, flag);

  auto cvt=[&](const void* s, float* d, size_t n){
    k_cvt<<<dim3((unsigned)((n+255)/256)),dim3(256),0,stream>>>(s,d,(int)n,flag);
  };
  cvt(d_in[0], X[0], 32ull*4*2048*3);
  for(int l=0;l<6;l++){
    cvt(d_in[di[l]], Wd[l], (size_t)midv[l]*3);
    if(cinv[l]) cvt(d_in[fi[l]], Wf[l], (size_t)midv[l]*cinv[l]);
    cvt(d_in[ti[l]], Wt[l], (size_t)coutv[l]*tkv[l]*midv[l]);
  }
  cvt(d_in[19], fcw, 1024ull*2048);
  cvt(d_in[20], fcb, 1024);

  struct PairT{int j,i;};
  const int Tcenters[6][4]={{0,1,2,3},{0,2,0,0},{0,1,0,0},{0,0,0,0},{0,0,0,0},{0,0,0,0}};
  const int npairs[6][4]={{1,1,1,1},{2,3,0,0},{2,2,0,0},{2,0,0,0},{1,0,0,0},{1,0,0,0}};
  const PairT pr[6][4][3]={
    { {{0,0},{0,0},{0,0}}, {{0,1},{0,0},{0,0}}, {{0,2},{0,0},{0,0}}, {{0,3},{0,0},{0,0}} },
    { {{1,0},{2,1},{0,0}}, {{0,1},{1,2},{2,3}}, {{0,0},{0,0},{0,0}}, {{0,0},{0,0},{0,0}} },
    { {{1,0},{2,1},{0,0}}, {{0,0},{1,1},{0,0}}, {{0,0},{0,0},{0,0}}, {{0,0},{0,0},{0,0}} },
    { {{1,0},{2,1},{0,0}}, {{0,0},{0,0},{0,0}}, {{0,0},{0,0},{0,0}}, {{0,0},{0,0},{0,0}} },
    { {{1,0},{0,0},{0,0}}, {{0,0},{0,0},{0,0}}, {{0,0},{0,0},{0,0}}, {{0,0},{0,0},{0,0}} },
    { {{0,0},{0,0},{0,0}}, {{0,0},{0,0},{0,0}}, {{0,0},{0,0},{0,0}}, {{0,0},{0,0},{0,0}} },
  };

  for(int l=0;l<6;l++){
    int N=Nv[l], m=mv[l], Lin=Lv[l], T=Tv[l], cin=cinv[l], mid=midv[l];
    int C=tkv[l]*midv[l], M=32*m, cout=coutv[l];
    float r2=rrv[l]*rrv[l];
    const float* Xin=X[l]; float* Xout=X[l+1];

    {
      dim3 g(32*T), blk(256);
      int a0=Tcenters[l][0],a1=Tcenters[l][1],a2=Tcenters[l][2],a3=Tcenters[l][3];
      if(N==2048)      k_fps<8><<<g,blk,0,stream>>>(Xin,Lin,N,m,a0,a1,a2,a3,T,Xout);
      else if(N==1024) k_fps<4><<<g,blk,0,stream>>>(Xin,Lin,N,m,a0,a1,a2,a3,T,Xout);
      else if(N==512)  k_fps<2><<<g,blk,0,stream>>>(Xin,Lin,N,m,a0,a1,a2,a3,T,Xout);
      else             k_fps<1><<<g,blk,0,stream>>>(Xin,Lin,N,m,a0,a1,a2,a3,T,Xout);
    }

    for(int tt=0; tt<T; ++tt){
      k_zero<<<dim3((unsigned)(((size_t)M*C+255)/256)),256,0,stream>>>(nf,(int)((size_t)M*C));
      k_zero<<<dim3((unsigned)((2*C+255)/256)),256,0,stream>>>(sums,2*C);
      const float* anc = Xout + (size_t)tt*m*3;
      size_t aBS=(size_t)T*m*3;
      for(int pi=0; pi<npairs[l][tt]; ++pi){
        int j=pr[l][tt][pi].j, i=pr[l][tt][pi].i;
        const float* pts = Xin + (size_t)i*N*3;
        size_t pBS=(size_t)Lin*N*3;
        int chunks=(m+255)>>8;
        k_bq<<<dim3(32*chunks),256,0,stream>>>(pts,anc,bq,N,m,r2,pBS,aBS);
        if(l==0){
          k_part0<<<dim3(M),64,0,stream>>>(pts,anc,bq,Wd[0],nf,m,mid,C,N-1,pBS,aBS);
        } else {
          const float* fin = F[l] + (size_t)i*N*cin;
          size_t fBS=(size_t)Lin*N*cin;
          k_pair<<<dim3(M/64,(mid+127)/128),256,0,stream>>>(
              fin,pts,anc,bq,Wf[l],Wd[l],nf,m,cin,mid,C,j*mid,N-1,fBS,pBS,aBS);
        }
      }
      k_bnstat<<<dim3((C+255)/256,32),256,0,stream>>>(nf,M,C,sums);
      k_bnapply<<<dim3((unsigned)(((size_t)M*C+255)/256)),256,0,stream>>>(nf,sums,M,C);
      float* outp = F[l+1] + (size_t)tt*m*cout;
      size_t oBS=(size_t)T*m*cout;
      if(l==0)
        k_gemm<64,false,true,false><<<dim3(M/64,cout/64),256,0,stream>>>(nf,Wt[l],nullptr,outp,M,C,cout,m,oBS,nullptr);
      else if(l<5)
        k_gemm<128,true,true,false><<<dim3(M/64,cout/128),256,0,stream>>>(nf,Wt[l],nullptr,outp,M,C,cout,m,oBS,nullptr);
      else
        k_gemm<128,true,false,false><<<dim3(M/64,cout/128),256,0,stream>>>(nf,Wt[l],nullptr,outp,M,C,cout,m,oBS,nullptr);
    }
  }

  k_gemm<128,true,false,true><<<dim3(4096/64,1024/128),256,0,stream>>>(
      F[6],fcw,fcb,d_out,4096,2048,1024,128,(size_t)128*1024,flag);
}

// Round 3
// 7555.611 us; speedup vs baseline: 1.5972x; 1.5972x over previous
//
#include <hip/hip_runtime.h>
#include <hip/hip_bf16.h>
#include <math.h>

typedef __hip_bfloat16 bf16;
typedef _Float16 f16;
typedef _Float16 f16x8 __attribute__((ext_vector_type(8)));
typedef float f32x4 __attribute__((ext_vector_type(4)));

// ---------------------------------------------------------------- dtype detect
__global__ void k_detect(const unsigned int* __restrict__ w, int nwords, int* __restrict__ flag){
  __shared__ int cnt;
  if(threadIdx.x==0) cnt=0;
  __syncthreads();
  int local=0;
  for(int i=threadIdx.x;i<nwords;i+=256){
    unsigned int v=w[i];
    int e=(v>>7)&0xFF;
    if(e>=0xC0) local++;
  }
  atomicAdd(&cnt, local);
  __syncthreads();
  if(threadIdx.x==0) flag[0] = (cnt > (nwords>>3)) ? 1 : 0;
}

// ---------------------------------------------------------------- converts
__global__ void k_cvt(const void* __restrict__ s, float* __restrict__ d, int n,
                      const int* __restrict__ flag){
  int i = blockIdx.x*256 + threadIdx.x;
  if(i>=n) return;
  if(*flag) d[i] = ((const float*)s)[i];
  else      d[i] = __bfloat162float(((const bf16*)s)[i]);
}

// convert to f16 with zero-pad to npad elements
__global__ void k_cvth(const void* __restrict__ s, f16* __restrict__ d, int nsrc, int npad,
                       const int* __restrict__ flag){
  int i = blockIdx.x*256 + threadIdx.x;
  if(i>=npad) return;
  float v=0.f;
  if(i<nsrc) v = (*flag)? ((const float*)s)[i] : __bfloat162float(((const bf16*)s)[i]);
  d[i]=(f16)v;
}

__global__ void k_zero(float* __restrict__ p, int n){
  int i = blockIdx.x*256 + threadIdx.x;
  if(i<n) p[i]=0.f;
}

// ---------------------------------------------------------------- FPS (exact f32)
template<int P>
__global__ __launch_bounds__(256) void k_fps(
    const float* __restrict__ xyz, int L, int N, int m,
    int c0,int c1,int c2,int c3, int T, float* __restrict__ anchors)
{
  int prob = blockIdx.x;
  int b = prob / T, tt = prob % T;
  int f = (tt==0)?c0:(tt==1)?c1:(tt==2)?c2:c3;
  const float* src = xyz + ((size_t)(b*L + f))*N*3;
  float* anc = anchors + ((size_t)(b*T + tt))*m*3;
  int tid = threadIdx.x;
  float px[P],py[P],pz[P],mind[P];
#pragma unroll
  for(int j=0;j<P;j++){
    int p = tid + j*256;
    px[j]=src[3*p]; py[j]=src[3*p+1]; pz[j]=src[3*p+2];
    mind[j]=1e10f;
  }
  __shared__ float sv[4]; __shared__ int si[4]; __shared__ float sl[3];
  if(tid==0){ anc[0]=px[0]; anc[1]=py[0]; anc[2]=pz[0]; sl[0]=px[0]; sl[1]=py[0]; sl[2]=pz[0]; }
  __syncthreads();
  float lx=sl[0], ly=sl[1], lz=sl[2];
  for(int it=1; it<m; ++it){
    float bv=-1.f, bx=0.f,by=0.f,bz=0.f; int bi=0;
#pragma unroll
    for(int j=0;j<P;j++){
#pragma clang fp contract(off)
      float dx=px[j]-lx, dy=py[j]-ly, dz=pz[j]-lz;
      float d2=dx*dx+dy*dy+dz*dz;
      float mv=mind[j]; if(d2<mv) mv=d2; mind[j]=mv;
      if(mv>bv){ bv=mv; bi=tid+j*256; bx=px[j]; by=py[j]; bz=pz[j]; }
    }
    float rv=bv; int ri=bi;
#pragma unroll
    for(int o=32;o>0;o>>=1){
      float ov=__shfl_down(rv,o); int oi=__shfl_down(ri,o);
      if(ov>rv || (ov==rv && oi<ri)){ rv=ov; ri=oi; }
    }
    if((tid&63)==0){ sv[tid>>6]=rv; si[tid>>6]=ri; }
    __syncthreads();
    float wv=sv[0]; int wi=si[0];
#pragma unroll
    for(int q=1;q<4;q++){
      if(sv[q]>wv || (sv[q]==wv && si[q]<wi)){ wv=sv[q]; wi=si[q]; }
    }
    if(tid==(wi&255)){
      sl[0]=bx; sl[1]=by; sl[2]=bz;
      anc[3*it]=bx; anc[3*it+1]=by; anc[3*it+2]=bz;
    }
    __syncthreads();
    lx=sl[0]; ly=sl[1]; lz=sl[2];
  }
}

// ---------------------------------------------------------------- ball query (exact f32)
__global__ __launch_bounds__(256) void k_bq(
    const float* __restrict__ pts, const float* __restrict__ anc,
    int* __restrict__ out, int N, int m, float r2,
    size_t pBS, size_t aBS)
{
  int chunks = (m+255)>>8;
  int b = blockIdx.x / chunks;
  int a = (blockIdx.x % chunks)*256 + threadIdx.x;
  const float* Pb = pts + (size_t)b*pBS;
  bool act = a < m;
  float ax=0,ay=0,az=0;
  int* o = out + ((size_t)b*m + (size_t)(act?a:0))*9;
  if(act){ const float* A = anc + (size_t)b*aBS + (size_t)a*3; ax=A[0]; ay=A[1]; az=A[2]; }
  int cnt = act?0:9, first=0;
  __shared__ float sp[768];
  for(int base=0; base<N; base+=256){
    for(int t=threadIdx.x; t<768; t+=256) sp[t]=Pb[(size_t)base*3+t];
    __syncthreads();
    for(int q=0;q<256;q++){
#pragma clang fp contract(off)
      float dx=sp[3*q]-ax, dy=sp[3*q+1]-ay, dz=sp[3*q+2]-az;
      float d2=dx*dx+dy*dy+dz*dz;
      if(d2<r2 && cnt<9){
        int p=base+q;
        if(cnt==0) first=p;
        o[cnt]=p; cnt++;
      }
    }
    if(__syncthreads_and(cnt>=9)) break;
  }
  if(act){ for(int k=cnt;k<9;k++) o[k]=first; }
}

// ---------------------------------------------------------------- layer 0 part (f32)
__global__ void k_part0(
    const float* __restrict__ pts, const float* __restrict__ anc,
    const int* __restrict__ idx, const float* __restrict__ Wd,
    float* __restrict__ nf, int m, int mid, int ld, int nmask,
    size_t pBS, size_t aBS)
{
  int row = blockIdx.x;
  int b = row/m, mm = row - b*m;
  int o = threadIdx.x;
  const float* A = anc + (size_t)b*aBS + (size_t)mm*3;
  float ax=A[0], ay=A[1], az=A[2];
  float w0=0,w1=0,w2=0;
  if(o<mid){ w0=Wd[3*o]; w1=Wd[3*o+1]; w2=Wd[3*o+2]; }
  const int* id = idx + (size_t)row*9;
  const float* Pb = pts + (size_t)b*pBS;
  float acc=0.f;
  for(int k=0;k<9;k++){
    int p=id[k] & nmask;
    const float* q = Pb + (size_t)p*3;
    float dx=q[0]-ax, dy=q[1]-ay, dz=q[2]-az;
    acc += dx*w0+dy*w1+dz*w2;
  }
  if(o<mid) nf[(size_t)row*ld + o] = acc;
}

// ---------------------------------------------------------------- MFMA pair kernel
// nf[:, jofs:jofs+mid] = sum_k (gather(feats,idx_k) @ Wf^T) * (disp_k @ Wd^T)
// 128x128 block tile, 4 waves of 64x64, f16 MFMA, f32 accumulate, f32 d-multiplier.
__global__ __launch_bounds__(256) void k_pair_mfma(
    const float* __restrict__ feats, const float* __restrict__ pts,
    const float* __restrict__ anc, const int* __restrict__ idx,
    const f16* __restrict__ Wfh, const float* __restrict__ Wd,
    float* __restrict__ nf, int m, int cin, int mid, int ld, int jofs, int nmask,
    size_t fBS, size_t pBS, size_t aBS)
{
  __shared__ f16 As[128*40];       // 80B row pitch -> 2-way bank aliasing (free)
  __shared__ f16 Bs[128*40];
  __shared__ float dispS[128][4];
  __shared__ float ancS[128][3];
  __shared__ int  idxS[128];
  int tid=threadIdx.x;
  int lane=tid&63, w=tid>>6;
  int quad=lane>>4, l15=lane&15;
  int rowOff=(w>>1)*64, colOff=(w&1)*64;
  int rowBase=blockIdx.x*128, colBase=blockIdx.y*128;
  int b=rowBase/m;                 // m%128==0 so a tile never crosses b
  const float* fB=feats+(size_t)b*fBS;
  const float* pB=pts+(size_t)b*pBS;
  if(tid<128){
    int mm=(rowBase+tid)-b*m;
    const float* A0=anc+(size_t)b*aBS+(size_t)mm*3;
    ancS[tid][0]=A0[0]; ancS[tid][1]=A0[1]; ancS[tid][2]=A0[2];
  }
  float wdv[4][3];
#pragma unroll
  for(int ctl=0;ctl<4;ctl++){
    int col=colBase+colOff+ctl*16+l15;
    if(col<mid){ wdv[ctl][0]=Wd[3*col]; wdv[ctl][1]=Wd[3*col+1]; wdv[ctl][2]=Wd[3*col+2]; }
    else { wdv[ctl][0]=0.f; wdv[ctl][1]=0.f; wdv[ctl][2]=0.f; }
  }
  f32x4 acc[4][4];
#pragma unroll
  for(int i=0;i<4;i++)
#pragma unroll
    for(int j=0;j<4;j++) acc[i][j]=(f32x4){0.f,0.f,0.f,0.f};
  int nct=cin>>5;
  int srow=tid>>1, shalf=tid&1;
  const int* idxB = idx + (size_t)rowBase*9;
  for(int k=0;k<9;k++){
    __syncthreads();                    // dispS/idxS rewrite vs previous epilogue / As,Bs reads
    if(tid<128){
      int p=idxB[tid*9+k]&nmask;
      idxS[tid]=p;
      const float* q=pB+(size_t)p*3;
      dispS[tid][0]=q[0]-ancS[tid][0];
      dispS[tid][1]=q[1]-ancS[tid][1];
      dispS[tid][2]=q[2]-ancS[tid][2];
      dispS[tid][3]=0.f;
    }
    f32x4 S[4][4];
#pragma unroll
    for(int i=0;i<4;i++)
#pragma unroll
      for(int j=0;j<4;j++) S[i][j]=(f32x4){0.f,0.f,0.f,0.f};
    for(int ct=0;ct<nct;ct++){
      __syncthreads();
      { // A stage: gather feats row, cvt f32->f16
        int p=idxS[srow];
        const float* src=fB+(size_t)p*cin+(ct<<5)+(shalf<<4);
        float4 v0=((const float4*)src)[0];
        float4 v1=((const float4*)src)[1];
        float4 v2=((const float4*)src)[2];
        float4 v3=((const float4*)src)[3];
        f16x8 h0, h1;
        h0[0]=(f16)v0.x; h0[1]=(f16)v0.y; h0[2]=(f16)v0.z; h0[3]=(f16)v0.w;
        h0[4]=(f16)v1.x; h0[5]=(f16)v1.y; h0[6]=(f16)v1.z; h0[7]=(f16)v1.w;
        h1[0]=(f16)v2.x; h1[1]=(f16)v2.y; h1[2]=(f16)v2.z; h1[3]=(f16)v2.w;
        h1[4]=(f16)v3.x; h1[5]=(f16)v3.y; h1[6]=(f16)v3.z; h1[7]=(f16)v3.w;
        *(f16x8*)(As + srow*40 + (shalf<<4))     = h0;
        *(f16x8*)(As + srow*40 + (shalf<<4) + 8) = h1;
      }
      { // B stage: Wfh (pre-converted, zero-padded rows) straight copy
        const uint4* s=(const uint4*)(Wfh+(size_t)(colBase+srow)*cin+(ct<<5)+(shalf<<4));
        uint4 u0=s[0], u1=s[1];
        *(uint4*)(Bs + srow*40 + (shalf<<4))     = u0;
        *(uint4*)(Bs + srow*40 + (shalf<<4) + 8) = u1;
      }
      __syncthreads();
      f16x8 af[4], bf4[4];
#pragma unroll
      for(int rt=0;rt<4;rt++) af[rt]=*(const f16x8*)(As + (rowOff+rt*16+l15)*40 + quad*8);
#pragma unroll
      for(int ctl=0;ctl<4;ctl++) bf4[ctl]=*(const f16x8*)(Bs + (colOff+ctl*16+l15)*40 + quad*8);
#pragma unroll
      for(int rt=0;rt<4;rt++)
#pragma unroll
        for(int ctl=0;ctl<4;ctl++)
          S[rt][ctl]=__builtin_amdgcn_mfma_f32_16x16x32_f16(af[rt],bf4[ctl],S[rt][ctl],0,0,0);
    }
    // epilogue: acc += S * (disp . Wd)
#pragma unroll
    for(int rt=0;rt<4;rt++){
#pragma unroll
      for(int r=0;r<4;r++){
        int rl=rowOff+rt*16+quad*4+r;
        float4 dv=*(const float4*)dispS[rl];
#pragma unroll
        for(int ctl=0;ctl<4;ctl++){
          float d=dv.x*wdv[ctl][0]+dv.y*wdv[ctl][1]+dv.z*wdv[ctl][2];
          acc[rt][ctl][r]+=S[rt][ctl][r]*d;
        }
      }
    }
  }
#pragma unroll
  for(int rt=0;rt<4;rt++){
#pragma unroll
    for(int r=0;r<4;r++){
      int row=rowBase+rowOff+rt*16+quad*4+r;
#pragma unroll
      for(int ctl=0;ctl<4;ctl++){
        int col=colBase+colOff+ctl*16+l15;
        if(col<mid) nf[(size_t)row*ld + jofs + col]=acc[rt][ctl][r];
      }
    }
  }
}

// ---------------------------------------------------------------- MFMA GEMM: out = act(A @ Bh^T + bias)
// A f32 (M x K, K%32==0), Bh f16 (N x K), 128x128 tile.
template<bool RELU, bool DYN>
__global__ __launch_bounds__(256) void k_gemm_mfma(
    const float* __restrict__ Ag, const f16* __restrict__ Bh,
    const float* __restrict__ bias, void* __restrict__ out,
    int M, int K, int N, int mloc, size_t oBS, const int* __restrict__ oflag)
{
  __shared__ f16 As[128*40];
  __shared__ f16 Bs[128*40];
  int tid=threadIdx.x;
  int lane=tid&63, w=tid>>6;
  int quad=lane>>4, l15=lane&15;
  int rowOff=(w>>1)*64, colOff=(w&1)*64;
  int rowBase=blockIdx.x*128, colBase=blockIdx.y*128;
  f32x4 acc[4][4];
#pragma unroll
  for(int i=0;i<4;i++)
#pragma unroll
    for(int j=0;j<4;j++) acc[i][j]=(f32x4){0.f,0.f,0.f,0.f};
  int nct=K>>5;
  int srow=tid>>1, shalf=tid&1;
  for(int ct=0;ct<nct;ct++){
    __syncthreads();
    {
      const float* src=Ag+(size_t)(rowBase+srow)*K+(ct<<5)+(shalf<<4);
      float4 v0=((const float4*)src)[0];
      float4 v1=((const float4*)src)[1];
      float4 v2=((const float4*)src)[2];
      float4 v3=((const float4*)src)[3];
      f16x8 h0, h1;
      h0[0]=(f16)v0.x; h0[1]=(f16)v0.y; h0[2]=(f16)v0.z; h0[3]=(f16)v0.w;
      h0[4]=(f16)v1.x; h0[5]=(f16)v1.y; h0[6]=(f16)v1.z; h0[7]=(f16)v1.w;
      h1[0]=(f16)v2.x; h1[1]=(f16)v2.y; h1[2]=(f16)v2.z; h1[3]=(f16)v2.w;
      h1[4]=(f16)v3.x; h1[5]=(f16)v3.y; h1[6]=(f16)v3.z; h1[7]=(f16)v3.w;
      *(f16x8*)(As + srow*40 + (shalf<<4))     = h0;
      *(f16x8*)(As + srow*40 + (shalf<<4) + 8) = h1;
    }
    {
      const uint4* s=(const uint4*)(Bh+(size_t)(colBase+srow)*K+(ct<<5)+(shalf<<4));
      uint4 u0=s[0], u1=s[1];
      *(uint4*)(Bs + srow*40 + (shalf<<4))     = u0;
      *(uint4*)(Bs + srow*40 + (shalf<<4) + 8) = u1;
    }
    __syncthreads();
    f16x8 af[4], bf4[4];
#pragma unroll
    for(int rt=0;rt<4;rt++) af[rt]=*(const f16x8*)(As + (rowOff+rt*16+l15)*40 + quad*8);
#pragma unroll
    for(int ctl=0;ctl<4;ctl++) bf4[ctl]=*(const f16x8*)(Bs + (colOff+ctl*16+l15)*40 + quad*8);
#pragma unroll
    for(int rt=0;rt<4;rt++)
#pragma unroll
      for(int ctl=0;ctl<4;ctl++)
        acc[rt][ctl]=__builtin_amdgcn_mfma_f32_16x16x32_f16(af[rt],bf4[ctl],acc[rt][ctl],0,0,0);
  }
  bool f32m = DYN ? (*oflag!=0) : true;
#pragma unroll
  for(int rt=0;rt<4;rt++){
#pragma unroll
    for(int r=0;r<4;r++){
      int row=rowBase+rowOff+rt*16+quad*4+r;
      int rb=row/mloc, rm=row-rb*mloc;
      size_t obase=(size_t)rb*oBS + (size_t)rm*N;
#pragma unroll
      for(int ctl=0;ctl<4;ctl++){
        int col=colBase+colOff+ctl*16+l15;
        float v=acc[rt][ctl][r];
        if(bias) v+=bias[col];
        if(RELU) v=fmaxf(v,0.f);
        if(DYN && !f32m) ((bf16*)out)[obase+col]=__float2bfloat16(v);
        else             ((float*)out)[obase+col]=v;
      }
    }
  }
}

// ---------------------------------------------------------------- BatchNorm
__global__ void k_bnstat(const float* __restrict__ nf, int M, int C, float* __restrict__ sums){
  int c = blockIdx.x*256 + threadIdx.x;
  if(c>=C) return;
  int rows = M>>5;
  int r0 = blockIdx.y*rows, r1 = r0+rows;
  float s=0.f, s2=0.f;
  for(int r=r0;r<r1;r++){
    float v=nf[(size_t)r*C+c];
    s+=v; s2+=v*v;
  }
  atomicAdd(&sums[c], s);
  atomicAdd(&sums[C+c], s2);
}

__global__ void k_bnapply(float* __restrict__ nf, const float* __restrict__ sums, int M, int C){
  long long i = (long long)blockIdx.x*256 + threadIdx.x;
  long long tot = (long long)M*C;
  if(i>=tot) return;
  int c = (int)(i % (long long)C);
  float mean = sums[c]/(float)M;
  float var = sums[C+c]/(float)M - mean*mean;
  if(var<0.f) var=0.f;
  float v = (nf[i]-mean)/sqrtf(var+1e-5f);
  nf[i] = v>0.f? v:0.f;
}

// ---------------------------------------------------------------- f32 GEMM (layer 0 temporal only, K=45)
template<int TN, bool ALIGNED, bool RELU>
__global__ __launch_bounds__(256) void k_gemm(
    const float* __restrict__ Ag, const float* __restrict__ Wg,
    const float* __restrict__ bias, float* __restrict__ out,
    int M, int K, int N, int mloc, size_t oBS)
{
  constexpr int CW = TN/16;
  __shared__ alignas(16) float As[16][64];
  __shared__ alignas(16) float Bs[16][TN];
  int tid=threadIdx.x, tx=tid&15, ty=tid>>4;
  int rowBase=blockIdx.x*64, colBase=blockIdx.y*TN;
  float acc[4][CW];
#pragma unroll
  for(int i=0;i<4;i++)
#pragma unroll
    for(int j=0;j<CW;j++) acc[i][j]=0.f;
  int lrow=tid&63, lcq=tid>>6;
  int nct=(K+15)>>4;
  for(int ct=0;ct<nct;ct++){
    __syncthreads();
    {
      int r=rowBase+lrow, c0=(ct<<4)+(lcq<<2);
#pragma unroll
      for(int q=0;q<4;q++){
        int c=c0+q;
        As[(lcq<<2)+q][lrow] = (ALIGNED||c<K)? Ag[(size_t)r*K+c] : 0.f;
      }
    }
    {
      int og=colBase+lrow, c0=(ct<<4)+(lcq<<2);
#pragma unroll
      for(int q=0;q<4;q++){
        int c=c0+q;
        Bs[(lcq<<2)+q][lrow] = (ALIGNED||c<K)? Wg[(size_t)og*K+c] : 0.f;
      }
    }
    __syncthreads();
#pragma unroll
    for(int c=0;c<16;c++){
      float4 a4=*(const float4*)&As[c][ty<<2];
      float av[4]={a4.x,a4.y,a4.z,a4.w};
      float bw[CW];
#pragma unroll
      for(int j0=0;j0<CW;j0+=4){
        float4 b4=*(const float4*)&Bs[c][tx*CW+j0];
        bw[j0]=b4.x; bw[j0+1]=b4.y; bw[j0+2]=b4.z; bw[j0+3]=b4.w;
      }
#pragma unroll
      for(int i=0;i<4;i++)
#pragma unroll
        for(int j=0;j<CW;j++) acc[i][j]+=av[i]*bw[j];
    }
  }
#pragma unroll
  for(int i=0;i<4;i++){
    int r=rowBase+(ty<<2)+i;
    int rb=r/mloc, rm=r-rb*mloc;
    size_t obase=(size_t)rb*oBS + (size_t)rm*N;
#pragma unroll
    for(int j=0;j<CW;j++){
      int o=colBase+tx*CW+j;
      float v=acc[i][j];
      if(bias) v+=bias[o];
      if(RELU) v=fmaxf(v,0.f);
      out[obase+o]=v;
    }
  }
}

// ---------------------------------------------------------------- host
extern "C" void kernel_launch(void* const* d_in, const int* in_sizes, int n_in,
                              void* d_out, int out_size, void* d_ws, size_t ws_size,
                              hipStream_t stream) {
  (void)in_sizes; (void)n_in; (void)out_size; (void)ws_size;

  const int di[6] = {2,4,7,10,13,16};
  const int fi[6] = {-1,5,8,11,14,17};
  const int ti[6] = {3,6,9,12,15,18};

  const int midv[6]={45,96,192,384,768,1536};
  const int midp[6]={0,128,256,384,768,1536};     // padded to col-tile for MFMA (l>=1)
  const int cinv[6]={0,64,128,256,512,1024};
  const int coutv[6]={64,128,256,512,1024,2048};
  const int tkv[6]={1,3,3,3,3,1};
  const int Nv[6]={2048,1024,512,512,256,256};
  const int mv[6]={1024,512,512,256,256,128};
  const int Lv[6]={4,4,2,2,1,1};
  const int Tv[6]={4,2,2,1,1,1};
  const float rrv[6]={1.5f,3.f,3.f,6.f,6.f,6.f};

  float* ws=(float*)d_ws;
  size_t off=0;
  auto A=[&](size_t n)->float*{ float* p=ws+off; off+=(n+63)&~(size_t)63; return p; };
  auto Ah=[&](size_t n)->f16*{ return (f16*)A((n+1)/2); };

  int* flag=(int*)A(64);

  float *Wd[6]; f16 *Wfh[6], *Wth[6];
  float* Wt0;
  for(int l=0;l<6;l++){
    Wd[l]=A((size_t)midv[l]*3);
    Wfh[l]= cinv[l]? Ah((size_t)midp[l]*cinv[l]) : nullptr;
    Wth[l]= l? Ah((size_t)coutv[l]*tkv[l]*midv[l]) : nullptr;
  }
  Wt0=A((size_t)64*45);
  f16* fcwh=Ah(1024ull*2048);
  float* fcb=A(1024);

  float* X[7];
  X[0]=A(32ull*4*2048*3);
  for(int l=0;l<6;l++) X[l+1]=A((size_t)32*Tv[l]*mv[l]*3);

  float* FA=A(8388608);
  float* FB=A(8388608);
  float* F[7]; F[0]=nullptr;
  for(int l=0;l<6;l++) F[l+1]=(l%2==0)?FA:FB;

  float* nf=A(18874368);
  float* sums=A(4608);
  int* bq=(int*)A(32ull*1024*9);

  // ---- detect dtype, convert weights
  k_detect<<<dim3(1),dim3(256),0,stream>>>((const unsigned int*)d_in[0], 4096, flag);

  auto cvt=[&](const void* s, float* d, size_t n){
    k_cvt<<<dim3((unsigned)((n+255)/256)),dim3(256),0,stream>>>(s,d,(int)n,flag);
  };
  auto cvth=[&](const void* s, f16* d, size_t nsrc, size_t npad){
    k_cvth<<<dim3((unsigned)((npad+255)/256)),dim3(256),0,stream>>>(s,d,(int)nsrc,(int)npad,flag);
  };
  cvt(d_in[0], X[0], 32ull*4*2048*3);
  for(int l=0;l<6;l++){
    cvt(d_in[di[l]], Wd[l], (size_t)midv[l]*3);
    if(cinv[l]) cvth(d_in[fi[l]], Wfh[l], (size_t)midv[l]*cinv[l], (size_t)midp[l]*cinv[l]);
    if(l) cvth(d_in[ti[l]], Wth[l], (size_t)coutv[l]*tkv[l]*midv[l], (size_t)coutv[l]*tkv[l]*midv[l]);
  }
  cvt(d_in[3], Wt0, 64*45);
  cvth(d_in[19], fcwh, 1024ull*2048, 1024ull*2048);
  cvt(d_in[20], fcb, 1024);

  struct PairT{int j,i;};
  const int Tcenters[6][4]={{0,1,2,3},{0,2,0,0},{0,1,0,0},{0,0,0,0},{0,0,0,0},{0,0,0,0}};
  const int npairs[6][4]={{1,1,1,1},{2,3,0,0},{2,2,0,0},{2,0,0,0},{1,0,0,0},{1,0,0,0}};
  const PairT pr[6][4][3]={
    { {{0,0},{0,0},{0,0}}, {{0,1},{0,0},{0,0}}, {{0,2},{0,0},{0,0}}, {{0,3},{0,0},{0,0}} },
    { {{1,0},{2,1},{0,0}}, {{0,1},{1,2},{2,3}}, {{0,0},{0,0},{0,0}}, {{0,0},{0,0},{0,0}} },
    { {{1,0},{2,1},{0,0}}, {{0,0},{1,1},{0,0}}, {{0,0},{0,0},{0,0}}, {{0,0},{0,0},{0,0}} },
    { {{1,0},{2,1},{0,0}}, {{0,0},{0,0},{0,0}}, {{0,0},{0,0},{0,0}}, {{0,0},{0,0},{0,0}} },
    { {{1,0},{0,0},{0,0}}, {{0,0},{0,0},{0,0}}, {{0,0},{0,0},{0,0}}, {{0,0},{0,0},{0,0}} },
    { {{0,0},{0,0},{0,0}}, {{0,0},{0,0},{0,0}}, {{0,0},{0,0},{0,0}}, {{0,0},{0,0},{0,0}} },
  };

  for(int l=0;l<6;l++){
    int N=Nv[l], m=mv[l], Lin=Lv[l], T=Tv[l], cin=cinv[l], mid=midv[l];
    int C=tkv[l]*midv[l], M=32*m, cout=coutv[l];
    float r2=rrv[l]*rrv[l];
    const float* Xin=X[l]; float* Xout=X[l+1];

    {
      dim3 g(32*T), blk(256);
      int a0=Tcenters[l][0],a1=Tcenters[l][1],a2=Tcenters[l][2],a3=Tcenters[l][3];
      if(N==2048)      k_fps<8><<<g,blk,0,stream>>>(Xin,Lin,N,m,a0,a1,a2,a3,T,Xout);
      else if(N==1024) k_fps<4><<<g,blk,0,stream>>>(Xin,Lin,N,m,a0,a1,a2,a3,T,Xout);
      else if(N==512)  k_fps<2><<<g,blk,0,stream>>>(Xin,Lin,N,m,a0,a1,a2,a3,T,Xout);
      else             k_fps<1><<<g,blk,0,stream>>>(Xin,Lin,N,m,a0,a1,a2,a3,T,Xout);
    }

    for(int tt=0; tt<T; ++tt){
      k_zero<<<dim3((unsigned)(((size_t)M*C+255)/256)),256,0,stream>>>(nf,(int)((size_t)M*C));
      k_zero<<<dim3((unsigned)((2*C+255)/256)),256,0,stream>>>(sums,2*C);
      const float* anc = Xout + (size_t)tt*m*3;
      size_t aBS=(size_t)T*m*3;
      for(int pi=0; pi<npairs[l][tt]; ++pi){
        int j=pr[l][tt][pi].j, i=pr[l][tt][pi].i;
        const float* pts = Xin + (size_t)i*N*3;
        size_t pBS=(size_t)Lin*N*3;
        int chunks=(m+255)>>8;
        k_bq<<<dim3(32*chunks),256,0,stream>>>(pts,anc,bq,N,m,r2,pBS,aBS);
        if(l==0){
          k_part0<<<dim3(M),64,0,stream>>>(pts,anc,bq,Wd[0],nf,m,mid,C,N-1,pBS,aBS);
        } else {
          const float* fin = F[l] + (size_t)i*N*cin;
          size_t fBS=(size_t)Lin*N*cin;
          k_pair_mfma<<<dim3(M/128, midp[l]/128),256,0,stream>>>(
              fin,pts,anc,bq,Wfh[l],Wd[l],nf,m,cin,mid,C,j*mid,N-1,fBS,pBS,aBS);
        }
      }
      k_bnstat<<<dim3((C+255)/256,32),256,0,stream>>>(nf,M,C,sums);
      k_bnapply<<<dim3((unsigned)(((size_t)M*C+255)/256)),256,0,stream>>>(nf,sums,M,C);
      float* outp = F[l+1] + (size_t)tt*m*cout;
      size_t oBS=(size_t)T*m*cout;
      if(l==0)
        k_gemm<64,false,true><<<dim3(M/64,cout/64),256,0,stream>>>(nf,Wt0,nullptr,outp,M,C,cout,m,oBS);
      else if(l<5)
        k_gemm_mfma<true,false><<<dim3(M/128,cout/128),256,0,stream>>>(nf,Wth[l],nullptr,outp,M,C,cout,m,oBS,nullptr);
      else
        k_gemm_mfma<false,false><<<dim3(M/128,cout/128),256,0,stream>>>(nf,Wth[l],nullptr,outp,M,C,cout,m,oBS,nullptr);
    }
  }

  // final FC -> d_out (bf16 or f32 per flag)
  k_gemm_mfma<false,true><<<dim3(4096/128,1024/128),256,0,stream>>>(
      F[6],fcwh,fcb,d_out,4096,2048,1024,128,(size_t)128*1024,flag);
}